// Round 2
// baseline (2325.404 us; speedup 1.0000x reference)
//
#include <hip/hip_runtime.h>

typedef unsigned short u16;
typedef __attribute__((ext_vector_type(8))) short bf16x8;
typedef __attribute__((ext_vector_type(4))) float f32x4;

struct __align__(8) U16x4 { u16 x, y, z, w; };

__device__ __forceinline__ u16 f2bf(float f) {
  unsigned u = __float_as_uint(f);
  u = (u + 0x7FFFu + ((u >> 16) & 1u)) >> 16;
  return (u16)u;
}

// ---------------- constants ----------------
// B=64, H=W=56, C=256, WS=7, SHIFT=3, HEADS=8, N=49, HID=1024
// M = B * nW * N = 64*64*49 = 200704 tokens (window order)
#define MTOK 200704
#define CDIM 256
#define NC3  768
#define HIDD 1024

// ws layout (bytes)
#define OFF_QKV   0UL                  // 200704*768*2 = 308281344
#define OFF_O     308281344UL          // 200704*256*2 = 102760448
#define OFF_H1    0UL                  // aliases qkv+o = 411041792
#define OFF_Y     411041792UL          // 200704*256*2
#define OFF_WQ    513802240UL          // 196608*2
#define OFF_WP    514195456UL          // 65536*2
#define OFF_W1    514326528UL          // 262144*2
#define OFF_W2    514850816UL          // 262144*2
#define OFF_RPB   515375104UL          // 8*2401*4

// ---------------- prep: weights f32->bf16, rpb gather ----------------
__global__ __launch_bounds__(256) void prep_kernel(
    const float* __restrict__ qkv_w, const float* __restrict__ proj_w,
    const float* __restrict__ fc1_w, const float* __restrict__ fc2_w,
    const float* __restrict__ rpb_table, const int* __restrict__ rel_index,
    u16* wq, u16* wp, u16* w1, u16* w2, float* rpbf) {
  int i = blockIdx.x * 256 + threadIdx.x;
  if (i < 196608) { wq[i] = f2bf(qkv_w[i]); return; }
  int j = i - 196608;
  if (j < 65536) { wp[j] = f2bf(proj_w[j]); return; }
  int k = j - 65536;
  if (k < 262144) { w1[k] = f2bf(fc1_w[k]); return; }
  int l = k - 262144;
  if (l < 262144) { w2[l] = f2bf(fc2_w[l]); return; }
  int r = l - 262144;
  if (r < 8 * 2401) {
    int h = r / 2401, nm = r % 2401;
    rpbf[r] = rpb_table[rel_index[nm] * 8 + h];
  }
}

// ---------------- LN1 + cyclic shift + window partition -> bf16 ----------------
__global__ __launch_bounds__(256) void ln1_kernel(const float* __restrict__ x,
                                                  const float* __restrict__ gg,
                                                  const float* __restrict__ bb,
                                                  u16* __restrict__ y) {
  int wid = threadIdx.x >> 6, lane = threadIdx.x & 63;
  int m = blockIdx.x * 4 + wid;            // window-order token
  int win = m / 49, n = m % 49;
  int b = win >> 6, widx = win & 63;
  int hh = (widx >> 3) * 7 + n / 7 + 3; if (hh >= 56) hh -= 56;
  int ww = (widx & 7) * 7 + n % 7 + 3; if (ww >= 56) ww -= 56;
  const float* src = x + ((size_t)b * 3136 + hh * 56 + ww) * CDIM + lane * 4;
  float4 v = *(const float4*)src;
  float s = v.x + v.y + v.z + v.w;
  float s2 = v.x * v.x + v.y * v.y + v.z * v.z + v.w * v.w;
  for (int o = 32; o; o >>= 1) { s += __shfl_xor(s, o); s2 += __shfl_xor(s2, o); }
  float mean = s * (1.f / 256.f);
  float inv = rsqrtf(s2 * (1.f / 256.f) - mean * mean + 1e-5f);
  int c = lane * 4;
  float4 gv = *(const float4*)(gg + c);
  float4 bv = *(const float4*)(bb + c);
  U16x4 o4;
  o4.x = f2bf((v.x - mean) * inv * gv.x + bv.x);
  o4.y = f2bf((v.y - mean) * inv * gv.y + bv.y);
  o4.z = f2bf((v.z - mean) * inv * gv.z + bv.z);
  o4.w = f2bf((v.w - mean) * inv * gv.w + bv.w);
  *(U16x4*)(y + (size_t)m * CDIM + c) = o4;
}

// ---------------- LN2 (no gather), reads x2 (f32, in d_out) ----------------
__global__ __launch_bounds__(256) void ln2_kernel(const float* __restrict__ x2,
                                                  const float* __restrict__ gg,
                                                  const float* __restrict__ bb,
                                                  u16* __restrict__ y) {
  int wid = threadIdx.x >> 6, lane = threadIdx.x & 63;
  int m = blockIdx.x * 4 + wid;
  const float* src = x2 + (size_t)m * CDIM + lane * 4;
  float4 v = *(const float4*)src;
  float s = v.x + v.y + v.z + v.w;
  float s2 = v.x * v.x + v.y * v.y + v.z * v.z + v.w * v.w;
  for (int o = 32; o; o >>= 1) { s += __shfl_xor(s, o); s2 += __shfl_xor(s2, o); }
  float mean = s * (1.f / 256.f);
  float inv = rsqrtf(s2 * (1.f / 256.f) - mean * mean + 1e-5f);
  int c = lane * 4;
  float4 gv = *(const float4*)(gg + c);
  float4 bv = *(const float4*)(bb + c);
  U16x4 o4;
  o4.x = f2bf((v.x - mean) * inv * gv.x + bv.x);
  o4.y = f2bf((v.y - mean) * inv * gv.y + bv.y);
  o4.z = f2bf((v.z - mean) * inv * gv.z + bv.z);
  o4.w = f2bf((v.w - mean) * inv * gv.w + bv.w);
  *(U16x4*)(y + (size_t)m * CDIM + c) = o4;
}

// ---------------- shared GEMM core: C[128x64] += A[M,K] * B[N,K]^T ----------------
// 4 waves, wave w owns rows [m0+32w, m0+32w+32), tiles: rt in {0,1}, ct in {0..3}
template <int K>
__device__ __forceinline__ void gemm_core(const u16* __restrict__ A, const u16* __restrict__ B,
                                          int m0, int n0, f32x4 acc[2][4]) {
  const int lane = threadIdx.x & 63;
  const int wid = threadIdx.x >> 6;
  const int lr = lane & 15, g = lane >> 4;
  const u16* a0p = A + (size_t)(m0 + wid * 32 + lr) * K;
  const u16* a1p = a0p + (size_t)16 * K;
  const u16* bp0 = B + (size_t)(n0 + lr) * K;
  const u16* bp1 = bp0 + (size_t)16 * K;
  const u16* bp2 = bp0 + (size_t)32 * K;
  const u16* bp3 = bp0 + (size_t)48 * K;
  const int kofs = 8 * g;
#pragma unroll 4
  for (int kk = 0; kk < K / 32; ++kk) {
    const int ko = kk * 32 + kofs;
    bf16x8 a0 = *(const bf16x8*)(a0p + ko);
    bf16x8 a1 = *(const bf16x8*)(a1p + ko);
    bf16x8 b0 = *(const bf16x8*)(bp0 + ko);
    bf16x8 b1 = *(const bf16x8*)(bp1 + ko);
    bf16x8 b2 = *(const bf16x8*)(bp2 + ko);
    bf16x8 b3 = *(const bf16x8*)(bp3 + ko);
    acc[0][0] = __builtin_amdgcn_mfma_f32_16x16x32_bf16(a0, b0, acc[0][0], 0, 0, 0);
    acc[1][0] = __builtin_amdgcn_mfma_f32_16x16x32_bf16(a1, b0, acc[1][0], 0, 0, 0);
    acc[0][1] = __builtin_amdgcn_mfma_f32_16x16x32_bf16(a0, b1, acc[0][1], 0, 0, 0);
    acc[1][1] = __builtin_amdgcn_mfma_f32_16x16x32_bf16(a1, b1, acc[1][1], 0, 0, 0);
    acc[0][2] = __builtin_amdgcn_mfma_f32_16x16x32_bf16(a0, b2, acc[0][2], 0, 0, 0);
    acc[1][2] = __builtin_amdgcn_mfma_f32_16x16x32_bf16(a1, b2, acc[1][2], 0, 0, 0);
    acc[0][3] = __builtin_amdgcn_mfma_f32_16x16x32_bf16(a0, b3, acc[0][3], 0, 0, 0);
    acc[1][3] = __builtin_amdgcn_mfma_f32_16x16x32_bf16(a1, b3, acc[1][3], 0, 0, 0);
  }
}

#define GEMM_PROLOG(KVAL)                                   \
  int m0 = blockIdx.y * 128, n0 = blockIdx.x * 64;          \
  f32x4 zero = {0.f, 0.f, 0.f, 0.f};                        \
  f32x4 acc[2][4] = {{zero, zero, zero, zero}, {zero, zero, zero, zero}}; \
  gemm_core<KVAL>(A, B, m0, n0, acc);                       \
  const int lane = threadIdx.x & 63;                        \
  const int wid = threadIdx.x >> 6;                         \
  const int lr = lane & 15, g = lane >> 4;

// qkv: out bf16 [M x 768]
__global__ __launch_bounds__(256) void gemm_qkv(const u16* __restrict__ A, const u16* __restrict__ B,
                                                const float* __restrict__ bias, u16* __restrict__ out) {
  GEMM_PROLOG(256)
#pragma unroll
  for (int rt = 0; rt < 2; ++rt)
#pragma unroll
    for (int reg = 0; reg < 4; ++reg) {
      int row = m0 + wid * 32 + rt * 16 + g * 4 + reg;
#pragma unroll
      for (int ct = 0; ct < 4; ++ct) {
        int col = n0 + ct * 16 + lr;
        out[(size_t)row * NC3 + col] = f2bf(acc[rt][ct][reg] + bias[col]);
      }
    }
}

// proj: window-reverse + reverse-shift scatter, x2 = x + proj_out  -> d_out (f32)
__global__ __launch_bounds__(256) void gemm_proj(const u16* __restrict__ A, const u16* __restrict__ B,
                                                 const float* __restrict__ bias,
                                                 const float* __restrict__ x, float* __restrict__ x2) {
  GEMM_PROLOG(256)
#pragma unroll
  for (int rt = 0; rt < 2; ++rt)
#pragma unroll
    for (int reg = 0; reg < 4; ++reg) {
      int row = m0 + wid * 32 + rt * 16 + g * 4 + reg;
      int win = row / 49, n = row % 49;
      int b = win >> 6, widx = win & 63;
      int hh = (widx >> 3) * 7 + n / 7 + 3; if (hh >= 56) hh -= 56;
      int ww = (widx & 7) * 7 + n % 7 + 3; if (ww >= 56) ww -= 56;
      size_t dst = ((size_t)b * 3136 + hh * 56 + ww) * CDIM;
#pragma unroll
      for (int ct = 0; ct < 4; ++ct) {
        int col = n0 + ct * 16 + lr;
        x2[dst + col] = x[dst + col] + acc[rt][ct][reg] + bias[col];
      }
    }
}

// fc1 + fast_gelu: out bf16 [M x 1024]
__global__ __launch_bounds__(256) void gemm_fc1(const u16* __restrict__ A, const u16* __restrict__ B,
                                                const float* __restrict__ bias, u16* __restrict__ out) {
  GEMM_PROLOG(256)
#pragma unroll
  for (int rt = 0; rt < 2; ++rt)
#pragma unroll
    for (int reg = 0; reg < 4; ++reg) {
      int row = m0 + wid * 32 + rt * 16 + g * 4 + reg;
#pragma unroll
      for (int ct = 0; ct < 4; ++ct) {
        int col = n0 + ct * 16 + lr;
        float v = acc[rt][ct][reg] + bias[col];
        v = v / (1.f + __expf(-1.702f * v));
        out[(size_t)row * HIDD + col] = f2bf(v);
      }
    }
}

// fc2 + residual (in-place on d_out which holds x2)
__global__ __launch_bounds__(256) void gemm_fc2(const u16* __restrict__ A, const u16* __restrict__ B,
                                                const float* __restrict__ bias, float* __restrict__ out) {
  GEMM_PROLOG(1024)
#pragma unroll
  for (int rt = 0; rt < 2; ++rt)
#pragma unroll
    for (int reg = 0; reg < 4; ++reg) {
      int row = m0 + wid * 32 + rt * 16 + g * 4 + reg;
#pragma unroll
      for (int ct = 0; ct < 4; ++ct) {
        int col = n0 + ct * 16 + lr;
        size_t idx = (size_t)row * CDIM + col;
        out[idx] = out[idx] + acc[rt][ct][reg] + bias[col];
      }
    }
}

// ---------------- windowed attention: 1 wave = 1 (window, head) ----------------
// N=49 padded to 64. S = q*k^T*scale + rpb + mask; softmax; O = P*v
__global__ __launch_bounds__(256) void attn_kernel(const u16* __restrict__ qkv,
                                                   const float* __restrict__ rpbf,
                                                   const float* __restrict__ mask,
                                                   u16* __restrict__ o) {
  __shared__ u16 p_lds[4][64][72];  // padded stride 72 to break bank conflicts
  const int lane = threadIdx.x & 63, wid = threadIdx.x >> 6;
  const int lr = lane & 15, g = lane >> 4;
  const int win = blockIdx.x >> 1;
  const int head = (blockIdx.x & 1) * 4 + wid;
  const int widx = win & 63;
  const size_t base = (size_t)win * 49 * NC3 + head * 32;

  // ---- S = q k^T ----
  bf16x8 aq[4], bk[4];
#pragma unroll
  for (int R = 0; R < 4; ++R) {
    int n = R * 16 + lr; if (n > 48) n = 48;
    aq[R] = *(const bf16x8*)(qkv + base + (size_t)n * NC3 + 8 * g);
  }
#pragma unroll
  for (int Cc = 0; Cc < 4; ++Cc) {
    int mi = Cc * 16 + lr; if (mi > 48) mi = 48;
    bk[Cc] = *(const bf16x8*)(qkv + base + 256 + (size_t)mi * NC3 + 8 * g);
  }
  f32x4 zero = {0.f, 0.f, 0.f, 0.f};
  f32x4 s[4][4] = {{zero, zero, zero, zero}, {zero, zero, zero, zero},
                   {zero, zero, zero, zero}, {zero, zero, zero, zero}};
#pragma unroll
  for (int R = 0; R < 4; ++R)
#pragma unroll
    for (int Cc = 0; Cc < 4; ++Cc)
      s[R][Cc] = __builtin_amdgcn_mfma_f32_16x16x32_bf16(aq[R], bk[Cc], s[R][Cc], 0, 0, 0);

  // ---- bias + mask + softmax (rows: R*16 + g*4 + reg; col of tile Cc: Cc*16+lr) ----
  const float scale = 0.17677669529663687f;  // 1/sqrt(32)
  const float* rpb_h = rpbf + head * 2401;
  const float* msk = mask + widx * 2401;
#pragma unroll
  for (int R = 0; R < 4; ++R) {
#pragma unroll
    for (int reg = 0; reg < 4; ++reg) {
      int n = R * 16 + g * 4 + reg;
      float mx = -1e30f;
#pragma unroll
      for (int Cc = 0; Cc < 4; ++Cc) {
        int mc = Cc * 16 + lr;
        float v;
        if (mc < 49)
          v = (n < 49) ? s[R][Cc][reg] * scale + rpb_h[n * 49 + mc] + msk[n * 49 + mc] : 0.f;
        else
          v = -1e30f;
        s[R][Cc][reg] = v;
        mx = fmaxf(mx, v);
      }
#pragma unroll
      for (int o_ = 1; o_ < 16; o_ <<= 1) mx = fmaxf(mx, __shfl_xor(mx, o_));
      float sum = 0.f;
#pragma unroll
      for (int Cc = 0; Cc < 4; ++Cc) {
        float p = __expf(s[R][Cc][reg] - mx);
        s[R][Cc][reg] = p;
        sum += p;
      }
#pragma unroll
      for (int o_ = 1; o_ < 16; o_ <<= 1) sum += __shfl_xor(sum, o_);
      float rs = 1.f / sum;
      int rowi = R * 16 + g * 4 + reg;
#pragma unroll
      for (int Cc = 0; Cc < 4; ++Cc) {
        int mc = Cc * 16 + lr;
        p_lds[wid][rowi][mc] = f2bf(s[R][Cc][reg] * rs);
      }
    }
  }
  __syncthreads();

  // ---- O = P v ----
  f32x4 oacc[4][2] = {{zero, zero}, {zero, zero}, {zero, zero}, {zero, zero}};
  const u16* vbase = qkv + base + 512;
#pragma unroll
  for (int ks = 0; ks < 2; ++ks) {
    bf16x8 bv[2];
#pragma unroll
    for (int D = 0; D < 2; ++D) {
#pragma unroll
      for (int i = 0; i < 8; ++i) {
        int mi = ks * 32 + 8 * g + i; if (mi > 48) mi = 48;  // P[*][mi>=49]==0
        bv[D][i] = (short)vbase[(size_t)mi * NC3 + D * 16 + lr];
      }
    }
#pragma unroll
    for (int R = 0; R < 4; ++R) {
      bf16x8 ap = *(const bf16x8*)(&p_lds[wid][R * 16 + lr][ks * 32 + 8 * g]);
      oacc[R][0] = __builtin_amdgcn_mfma_f32_16x16x32_bf16(ap, bv[0], oacc[R][0], 0, 0, 0);
      oacc[R][1] = __builtin_amdgcn_mfma_f32_16x16x32_bf16(ap, bv[1], oacc[R][1], 0, 0, 0);
    }
  }
#pragma unroll
  for (int R = 0; R < 4; ++R)
#pragma unroll
    for (int D = 0; D < 2; ++D)
#pragma unroll
      for (int reg = 0; reg < 4; ++reg) {
        int n = R * 16 + g * 4 + reg;
        if (n < 49)
          o[((size_t)win * 49 + n) * CDIM + head * 32 + D * 16 + lr] = f2bf(oacc[R][D][reg]);
      }
}

// ---------------- launch ----------------
extern "C" void kernel_launch(void* const* d_in, const int* in_sizes, int n_in,
                              void* d_out, int out_size, void* d_ws, size_t ws_size,
                              hipStream_t stream) {
  const float* x      = (const float*)d_in[0];
  const float* n1g    = (const float*)d_in[1];
  const float* n1b    = (const float*)d_in[2];
  const float* qkv_w  = (const float*)d_in[3];
  const float* qkv_b  = (const float*)d_in[4];
  const float* rpb_t  = (const float*)d_in[5];
  const float* proj_w = (const float*)d_in[6];
  const float* proj_b = (const float*)d_in[7];
  const float* n2g    = (const float*)d_in[8];
  const float* n2b    = (const float*)d_in[9];
  const float* fc1_w  = (const float*)d_in[10];
  const float* fc1_b  = (const float*)d_in[11];
  const float* fc2_w  = (const float*)d_in[12];
  const float* fc2_b  = (const float*)d_in[13];
  const int*   relidx = (const int*)d_in[14];
  const float* amask  = (const float*)d_in[15];
  float* out = (float*)d_out;
  char* ws = (char*)d_ws;

  u16* qkv_buf = (u16*)(ws + OFF_QKV);
  u16* o_buf   = (u16*)(ws + OFF_O);
  u16* h1_buf  = (u16*)(ws + OFF_H1);
  u16* y_buf   = (u16*)(ws + OFF_Y);
  u16* wq = (u16*)(ws + OFF_WQ);
  u16* wp = (u16*)(ws + OFF_WP);
  u16* w1 = (u16*)(ws + OFF_W1);
  u16* w2 = (u16*)(ws + OFF_W2);
  float* rpbf = (float*)(ws + OFF_RPB);

  prep_kernel<<<3148, 256, 0, stream>>>(qkv_w, proj_w, fc1_w, fc2_w, rpb_t, relidx, wq, wp, w1, w2, rpbf);
  ln1_kernel<<<MTOK / 4, 256, 0, stream>>>(x, n1g, n1b, y_buf);
  gemm_qkv<<<dim3(NC3 / 64, MTOK / 128), 256, 0, stream>>>(y_buf, wq, qkv_b, qkv_buf);
  attn_kernel<<<4096 * 2, 256, 0, stream>>>(qkv_buf, rpbf, amask, o_buf);
  gemm_proj<<<dim3(CDIM / 64, MTOK / 128), 256, 0, stream>>>(o_buf, wp, proj_b, x, out);
  ln2_kernel<<<MTOK / 4, 256, 0, stream>>>(out, n2g, n2b, y_buf);
  gemm_fc1<<<dim3(HIDD / 64, MTOK / 128), 256, 0, stream>>>(y_buf, w1, fc1_b, h1_buf);
  gemm_fc2<<<dim3(CDIM / 64, MTOK / 128), 256, 0, stream>>>(h1_buf, w2, fc2_b, out);
}

// Round 3
// 1414.603 us; speedup vs baseline: 1.6439x; 1.6439x over previous
//
#include <hip/hip_runtime.h>

typedef unsigned short u16;
typedef __attribute__((ext_vector_type(8))) short bf16x8;
typedef __attribute__((ext_vector_type(4))) float f32x4;

struct __align__(8) U16x4 { u16 x, y, z, w; };

__device__ __forceinline__ u16 f2bf(float f) {
  unsigned u = __float_as_uint(f);
  u = (u + 0x7FFFu + ((u >> 16) & 1u)) >> 16;
  return (u16)u;
}

// async global->LDS, 16B per lane (global_load_lds_dwordx4)
__device__ __forceinline__ void gload16(const u16* g, u16* l) {
  __builtin_amdgcn_global_load_lds((const __attribute__((address_space(1))) void*)g,
                                   (__attribute__((address_space(3))) void*)l, 16, 0, 0);
}

// ---------------- constants ----------------
#define MTOK 200704
#define CDIM 256
#define NC3  768
#define HIDD 1024

// ws layout (bytes)
#define OFF_QKV   0UL
#define OFF_O     308281344UL
#define OFF_H1    0UL
#define OFF_Y     411041792UL
#define OFF_WQ    513802240UL
#define OFF_WP    514195456UL
#define OFF_W1    514326528UL
#define OFF_W2    514850816UL
#define OFF_RPB   515375104UL

// ---------------- prep: weights f32->bf16, rpb gather ----------------
__global__ __launch_bounds__(256) void prep_kernel(
    const float* __restrict__ qkv_w, const float* __restrict__ proj_w,
    const float* __restrict__ fc1_w, const float* __restrict__ fc2_w,
    const float* __restrict__ rpb_table, const int* __restrict__ rel_index,
    u16* wq, u16* wp, u16* w1, u16* w2, float* rpbf) {
  int i = blockIdx.x * 256 + threadIdx.x;
  if (i < 196608) { wq[i] = f2bf(qkv_w[i]); return; }
  int j = i - 196608;
  if (j < 65536) { wp[j] = f2bf(proj_w[j]); return; }
  int k = j - 65536;
  if (k < 262144) { w1[k] = f2bf(fc1_w[k]); return; }
  int l = k - 262144;
  if (l < 262144) { w2[l] = f2bf(fc2_w[l]); return; }
  int r = l - 262144;
  if (r < 8 * 2401) {
    int h = r / 2401, nm = r % 2401;
    rpbf[r] = rpb_table[rel_index[nm] * 8 + h];
  }
}

// ---------------- LN1 + cyclic shift + window partition -> bf16 ----------------
__global__ __launch_bounds__(256) void ln1_kernel(const float* __restrict__ x,
                                                  const float* __restrict__ gg,
                                                  const float* __restrict__ bb,
                                                  u16* __restrict__ y) {
  int wid = threadIdx.x >> 6, lane = threadIdx.x & 63;
  int m = blockIdx.x * 4 + wid;            // window-order token
  int win = m / 49, n = m % 49;
  int b = win >> 6, widx = win & 63;
  int hh = (widx >> 3) * 7 + n / 7 + 3; if (hh >= 56) hh -= 56;
  int ww = (widx & 7) * 7 + n % 7 + 3; if (ww >= 56) ww -= 56;
  const float* src = x + ((size_t)b * 3136 + hh * 56 + ww) * CDIM + lane * 4;
  float4 v = *(const float4*)src;
  float s = v.x + v.y + v.z + v.w;
  float s2 = v.x * v.x + v.y * v.y + v.z * v.z + v.w * v.w;
  for (int o = 32; o; o >>= 1) { s += __shfl_xor(s, o); s2 += __shfl_xor(s2, o); }
  float mean = s * (1.f / 256.f);
  float inv = rsqrtf(s2 * (1.f / 256.f) - mean * mean + 1e-5f);
  int c = lane * 4;
  float4 gv = *(const float4*)(gg + c);
  float4 bv = *(const float4*)(bb + c);
  U16x4 o4;
  o4.x = f2bf((v.x - mean) * inv * gv.x + bv.x);
  o4.y = f2bf((v.y - mean) * inv * gv.y + bv.y);
  o4.z = f2bf((v.z - mean) * inv * gv.z + bv.z);
  o4.w = f2bf((v.w - mean) * inv * gv.w + bv.w);
  *(U16x4*)(y + (size_t)m * CDIM + c) = o4;
}

// ---------------- LN2 (no gather), reads x2 (f32, in d_out) ----------------
__global__ __launch_bounds__(256) void ln2_kernel(const float* __restrict__ x2,
                                                  const float* __restrict__ gg,
                                                  const float* __restrict__ bb,
                                                  u16* __restrict__ y) {
  int wid = threadIdx.x >> 6, lane = threadIdx.x & 63;
  int m = blockIdx.x * 4 + wid;
  const float* src = x2 + (size_t)m * CDIM + lane * 4;
  float4 v = *(const float4*)src;
  float s = v.x + v.y + v.z + v.w;
  float s2 = v.x * v.x + v.y * v.y + v.z * v.z + v.w * v.w;
  for (int o = 32; o; o >>= 1) { s += __shfl_xor(s, o); s2 += __shfl_xor(s2, o); }
  float mean = s * (1.f / 256.f);
  float inv = rsqrtf(s2 * (1.f / 256.f) - mean * mean + 1e-5f);
  int c = lane * 4;
  float4 gv = *(const float4*)(gg + c);
  float4 bv = *(const float4*)(bb + c);
  U16x4 o4;
  o4.x = f2bf((v.x - mean) * inv * gv.x + bv.x);
  o4.y = f2bf((v.y - mean) * inv * gv.y + bv.y);
  o4.z = f2bf((v.z - mean) * inv * gv.z + bv.z);
  o4.w = f2bf((v.w - mean) * inv * gv.w + bv.w);
  *(U16x4*)(y + (size_t)m * CDIM + c) = o4;
}

// ---------------- m97-style 128x128 LDS-staged GEMM core ----------------
// C[128x128] = A[M,K] * B[N,K]^T  tile at (m0,n0).
// 4 waves in 2x2; wave (wr,wc) owns 64x64; acc[4][4] of 16x16 frags.
// LDS: A-tile [128][32] + B-tile [128][32] bf16 (16 KB), single-buffered,
// 2 barriers per BK=32 step (m97 structure), global_load_lds width 16.
template <int K>
__device__ __forceinline__ void gemm_tile(const u16* __restrict__ A, const u16* __restrict__ B,
                                          int m0, int n0, f32x4 acc[4][4], u16* lds) {
  const int tid = threadIdx.x;
  const int lane = tid & 63;
  const int lr = lane & 15, g = lane >> 4;
  const int wid = tid >> 6, wr = wid >> 1, wc = wid & 1;
  u16* lds_a = lds;           // [128][32]
  u16* lds_b = lds + 4096;    // [128][32]
  const int srow = tid >> 2, schunk = tid & 3;   // stage: row (tid>>2)+{0,64}, 8-el chunk
  const u16* ga = A + (size_t)(m0 + srow) * K + schunk * 8;
  const u16* gb = B + (size_t)(n0 + srow) * K + schunk * 8;
  u16* la = lds_a + srow * 32 + schunk * 8;
  u16* lb = lds_b + srow * 32 + schunk * 8;

#pragma unroll 2
  for (int k0 = 0; k0 < K; k0 += 32) {
    gload16(ga + k0, la);
    gload16(ga + (size_t)64 * K + k0, la + 2048);
    gload16(gb + k0, lb);
    gload16(gb + (size_t)64 * K + k0, lb + 2048);
    __syncthreads();   // drains vmcnt + lgkmcnt, then barrier
    bf16x8 af[4], bfr[4];
#pragma unroll
    for (int i = 0; i < 4; ++i) {
      af[i]  = *(const bf16x8*)(lds_a + (wr * 64 + i * 16 + lr) * 32 + g * 8);
      bfr[i] = *(const bf16x8*)(lds_b + (wc * 64 + i * 16 + lr) * 32 + g * 8);
    }
#pragma unroll
    for (int i = 0; i < 4; ++i)
#pragma unroll
      for (int j = 0; j < 4; ++j)
        acc[i][j] = __builtin_amdgcn_mfma_f32_16x16x32_bf16(af[i], bfr[j], acc[i][j], 0, 0, 0);
    __syncthreads();   // protect LDS before next stage
  }
}

// XCD-aware swizzle (T1): consecutive logical tiles -> same XCD. nwg % 8 == 0 for all grids.
__device__ __forceinline__ int xcd_swz(int bid, int nwg) {
  return (bid & 7) * (nwg >> 3) + (bid >> 3);
}

#define GEMM_PROLOG(NVAL, KVAL)                                            \
  __shared__ u16 lds[8192];                                                \
  const int NTX = (NVAL) / 128;                                            \
  int logical = xcd_swz(blockIdx.x, NTX * (MTOK / 128));                   \
  int m0 = (logical / NTX) * 128, n0 = (logical % NTX) * 128;              \
  f32x4 zero = {0.f, 0.f, 0.f, 0.f};                                       \
  f32x4 acc[4][4] = {{zero, zero, zero, zero}, {zero, zero, zero, zero},   \
                     {zero, zero, zero, zero}, {zero, zero, zero, zero}};  \
  gemm_tile<KVAL>(A, B, m0, n0, acc, lds);                                 \
  const int lane = threadIdx.x & 63;                                       \
  const int lr = lane & 15, g = lane >> 4;                                 \
  const int wid = threadIdx.x >> 6, wr = wid >> 1, wc = wid & 1;

// qkv: out bf16 [M x 768], +bias
__global__ __launch_bounds__(256) void gemm_qkv(const u16* __restrict__ A, const u16* __restrict__ B,
                                                const float* __restrict__ bias, u16* __restrict__ out) {
  GEMM_PROLOG(NC3, 256)
#pragma unroll
  for (int i = 0; i < 4; ++i) {
    int row = m0 + wr * 64 + i * 16 + g * 4;
#pragma unroll
    for (int j = 0; j < 4; ++j) {
      int col = n0 + wc * 64 + j * 16 + lr;
      float bv = bias[col];
#pragma unroll
      for (int r = 0; r < 4; ++r)
        out[(size_t)(row + r) * NC3 + col] = f2bf(acc[i][j][r] + bv);
    }
  }
}

// proj: window-reverse + reverse-shift scatter, x2 = x + proj_out -> d_out (f32)
__global__ __launch_bounds__(256) void gemm_proj(const u16* __restrict__ A, const u16* __restrict__ B,
                                                 const float* __restrict__ bias,
                                                 const float* __restrict__ x, float* __restrict__ x2) {
  GEMM_PROLOG(CDIM, 256)
#pragma unroll
  for (int i = 0; i < 4; ++i) {
#pragma unroll
    for (int r = 0; r < 4; ++r) {
      int row = m0 + wr * 64 + i * 16 + g * 4 + r;
      int win = row / 49, n = row % 49;
      int b = win >> 6, widx = win & 63;
      int hh = (widx >> 3) * 7 + n / 7 + 3; if (hh >= 56) hh -= 56;
      int ww = (widx & 7) * 7 + n % 7 + 3; if (ww >= 56) ww -= 56;
      size_t dst = ((size_t)b * 3136 + hh * 56 + ww) * CDIM;
#pragma unroll
      for (int j = 0; j < 4; ++j) {
        int col = n0 + wc * 64 + j * 16 + lr;
        x2[dst + col] = x[dst + col] + acc[i][j][r] + bias[col];
      }
    }
  }
}

// fc1 + fast_gelu: out bf16 [M x 1024]
__global__ __launch_bounds__(256) void gemm_fc1(const u16* __restrict__ A, const u16* __restrict__ B,
                                                const float* __restrict__ bias, u16* __restrict__ out) {
  GEMM_PROLOG(HIDD, 256)
#pragma unroll
  for (int i = 0; i < 4; ++i) {
    int row = m0 + wr * 64 + i * 16 + g * 4;
#pragma unroll
    for (int j = 0; j < 4; ++j) {
      int col = n0 + wc * 64 + j * 16 + lr;
      float bv = bias[col];
#pragma unroll
      for (int r = 0; r < 4; ++r) {
        float v = acc[i][j][r] + bv;
        v = v / (1.f + __expf(-1.702f * v));
        out[(size_t)(row + r) * HIDD + col] = f2bf(v);
      }
    }
  }
}

// fc2 + residual (in-place on d_out which holds x2)
__global__ __launch_bounds__(256) void gemm_fc2(const u16* __restrict__ A, const u16* __restrict__ B,
                                                const float* __restrict__ bias, float* __restrict__ out) {
  GEMM_PROLOG(CDIM, 1024)
#pragma unroll
  for (int i = 0; i < 4; ++i) {
    int row = m0 + wr * 64 + i * 16 + g * 4;
#pragma unroll
    for (int j = 0; j < 4; ++j) {
      int col = n0 + wc * 64 + j * 16 + lr;
      float bv = bias[col];
#pragma unroll
      for (int r = 0; r < 4; ++r) {
        size_t idx = (size_t)(row + r) * CDIM + col;
        out[idx] = out[idx] + acc[i][j][r] + bv;
      }
    }
  }
}

// ---------------- windowed attention: 1 wave = 1 (window, head) ----------------
__global__ __launch_bounds__(256) void attn_kernel(const u16* __restrict__ qkv,
                                                   const float* __restrict__ rpbf,
                                                   const float* __restrict__ mask,
                                                   u16* __restrict__ o) {
  __shared__ u16 p_lds[4][64][72];
  const int lane = threadIdx.x & 63, wid = threadIdx.x >> 6;
  const int lr = lane & 15, g = lane >> 4;
  const int win = blockIdx.x >> 1;
  const int head = (blockIdx.x & 1) * 4 + wid;
  const int widx = win & 63;
  const size_t base = (size_t)win * 49 * NC3 + head * 32;

  bf16x8 aq[4], bk[4];
#pragma unroll
  for (int R = 0; R < 4; ++R) {
    int n = R * 16 + lr; if (n > 48) n = 48;
    aq[R] = *(const bf16x8*)(qkv + base + (size_t)n * NC3 + 8 * g);
  }
#pragma unroll
  for (int Cc = 0; Cc < 4; ++Cc) {
    int mi = Cc * 16 + lr; if (mi > 48) mi = 48;
    bk[Cc] = *(const bf16x8*)(qkv + base + 256 + (size_t)mi * NC3 + 8 * g);
  }
  f32x4 zero = {0.f, 0.f, 0.f, 0.f};
  f32x4 s[4][4] = {{zero, zero, zero, zero}, {zero, zero, zero, zero},
                   {zero, zero, zero, zero}, {zero, zero, zero, zero}};
#pragma unroll
  for (int R = 0; R < 4; ++R)
#pragma unroll
    for (int Cc = 0; Cc < 4; ++Cc)
      s[R][Cc] = __builtin_amdgcn_mfma_f32_16x16x32_bf16(aq[R], bk[Cc], s[R][Cc], 0, 0, 0);

  const float scale = 0.17677669529663687f;
  const float* rpb_h = rpbf + head * 2401;
  const float* msk = mask + widx * 2401;
#pragma unroll
  for (int R = 0; R < 4; ++R) {
#pragma unroll
    for (int reg = 0; reg < 4; ++reg) {
      int n = R * 16 + g * 4 + reg;
      float mx = -1e30f;
#pragma unroll
      for (int Cc = 0; Cc < 4; ++Cc) {
        int mc = Cc * 16 + lr;
        float v;
        if (mc < 49)
          v = (n < 49) ? s[R][Cc][reg] * scale + rpb_h[n * 49 + mc] + msk[n * 49 + mc] : 0.f;
        else
          v = -1e30f;
        s[R][Cc][reg] = v;
        mx = fmaxf(mx, v);
      }
#pragma unroll
      for (int o_ = 1; o_ < 16; o_ <<= 1) mx = fmaxf(mx, __shfl_xor(mx, o_));
      float sum = 0.f;
#pragma unroll
      for (int Cc = 0; Cc < 4; ++Cc) {
        float p = __expf(s[R][Cc][reg] - mx);
        s[R][Cc][reg] = p;
        sum += p;
      }
#pragma unroll
      for (int o_ = 1; o_ < 16; o_ <<= 1) sum += __shfl_xor(sum, o_);
      float rs = 1.f / sum;
      int rowi = R * 16 + g * 4 + reg;
#pragma unroll
      for (int Cc = 0; Cc < 4; ++Cc) {
        int mc = Cc * 16 + lr;
        p_lds[wid][rowi][mc] = f2bf(s[R][Cc][reg] * rs);
      }
    }
  }
  __syncthreads();

  f32x4 oacc[4][2] = {{zero, zero}, {zero, zero}, {zero, zero}, {zero, zero}};
  const u16* vbase = qkv + base + 512;
#pragma unroll
  for (int ks = 0; ks < 2; ++ks) {
    bf16x8 bv[2];
#pragma unroll
    for (int D = 0; D < 2; ++D) {
#pragma unroll
      for (int i = 0; i < 8; ++i) {
        int mi = ks * 32 + 8 * g + i; if (mi > 48) mi = 48;
        bv[D][i] = (short)vbase[(size_t)mi * NC3 + D * 16 + lr];
      }
    }
#pragma unroll
    for (int R = 0; R < 4; ++R) {
      bf16x8 ap = *(const bf16x8*)(&p_lds[wid][R * 16 + lr][ks * 32 + 8 * g]);
      oacc[R][0] = __builtin_amdgcn_mfma_f32_16x16x32_bf16(ap, bv[0], oacc[R][0], 0, 0, 0);
      oacc[R][1] = __builtin_amdgcn_mfma_f32_16x16x32_bf16(ap, bv[1], oacc[R][1], 0, 0, 0);
    }
  }
#pragma unroll
  for (int R = 0; R < 4; ++R)
#pragma unroll
    for (int D = 0; D < 2; ++D)
#pragma unroll
      for (int reg = 0; reg < 4; ++reg) {
        int n = R * 16 + g * 4 + reg;
        if (n < 49)
          o[((size_t)win * 49 + n) * CDIM + head * 32 + D * 16 + lr] = f2bf(oacc[R][D][reg]);
      }
}

// ---------------- launch ----------------
extern "C" void kernel_launch(void* const* d_in, const int* in_sizes, int n_in,
                              void* d_out, int out_size, void* d_ws, size_t ws_size,
                              hipStream_t stream) {
  const float* x      = (const float*)d_in[0];
  const float* n1g    = (const float*)d_in[1];
  const float* n1b    = (const float*)d_in[2];
  const float* qkv_w  = (const float*)d_in[3];
  const float* qkv_b  = (const float*)d_in[4];
  const float* rpb_t  = (const float*)d_in[5];
  const float* proj_w = (const float*)d_in[6];
  const float* proj_b = (const float*)d_in[7];
  const float* n2g    = (const float*)d_in[8];
  const float* n2b    = (const float*)d_in[9];
  const float* fc1_w  = (const float*)d_in[10];
  const float* fc1_b  = (const float*)d_in[11];
  const float* fc2_w  = (const float*)d_in[12];
  const float* fc2_b  = (const float*)d_in[13];
  const int*   relidx = (const int*)d_in[14];
  const float* amask  = (const float*)d_in[15];
  float* out = (float*)d_out;
  char* ws = (char*)d_ws;

  u16* qkv_buf = (u16*)(ws + OFF_QKV);
  u16* o_buf   = (u16*)(ws + OFF_O);
  u16* h1_buf  = (u16*)(ws + OFF_H1);
  u16* y_buf   = (u16*)(ws + OFF_Y);
  u16* wq = (u16*)(ws + OFF_WQ);
  u16* wp = (u16*)(ws + OFF_WP);
  u16* w1 = (u16*)(ws + OFF_W1);
  u16* w2 = (u16*)(ws + OFF_W2);
  float* rpbf = (float*)(ws + OFF_RPB);

  prep_kernel<<<3148, 256, 0, stream>>>(qkv_w, proj_w, fc1_w, fc2_w, rpb_t, relidx, wq, wp, w1, w2, rpbf);
  ln1_kernel<<<MTOK / 4, 256, 0, stream>>>(x, n1g, n1b, y_buf);
  gemm_qkv<<<(NC3 / 128) * (MTOK / 128), 256, 0, stream>>>(y_buf, wq, qkv_b, qkv_buf);
  attn_kernel<<<4096 * 2, 256, 0, stream>>>(qkv_buf, rpbf, amask, o_buf);
  gemm_proj<<<(CDIM / 128) * (MTOK / 128), 256, 0, stream>>>(o_buf, wp, proj_b, x, out);
  ln2_kernel<<<MTOK / 4, 256, 0, stream>>>(out, n2g, n2b, y_buf);
  gemm_fc1<<<(HIDD / 128) * (MTOK / 128), 256, 0, stream>>>(y_buf, w1, fc1_b, h1_buf);
  gemm_fc2<<<(CDIM / 128) * (MTOK / 128), 256, 0, stream>>>(h1_buf, w2, fc2_b, out);
}

// Round 4
// 1351.747 us; speedup vs baseline: 1.7203x; 1.0465x over previous
//
#include <hip/hip_runtime.h>

typedef unsigned short u16;
typedef __attribute__((ext_vector_type(8))) short bf16x8;
typedef __attribute__((ext_vector_type(4))) float f32x4;

struct __align__(8) U16x4 { u16 x, y, z, w; };

__device__ __forceinline__ u16 f2bf(float f) {
  unsigned u = __float_as_uint(f);
  u = (u + 0x7FFFu + ((u >> 16) & 1u)) >> 16;
  return (u16)u;
}

// async global->LDS, 16B per lane (global_load_lds_dwordx4)
__device__ __forceinline__ void gload16(const u16* g, u16* l) {
  __builtin_amdgcn_global_load_lds((const __attribute__((address_space(1))) void*)g,
                                   (__attribute__((address_space(3))) void*)l, 16, 0, 0);
}

// ---------------- constants ----------------
#define MTOK 200704
#define CDIM 256
#define NC3  768
#define HIDD 1024

// ws layout (bytes)
#define OFF_QKV   0UL
#define OFF_O     308281344UL
#define OFF_H1    0UL
#define OFF_Y     411041792UL
#define OFF_WQ    513802240UL
#define OFF_WP    514195456UL
#define OFF_W1    514326528UL
#define OFF_W2    514850816UL
#define OFF_RPB   515375104UL

// ---------------- prep: weights f32->bf16, rpb gather ----------------
__global__ __launch_bounds__(256) void prep_kernel(
    const float* __restrict__ qkv_w, const float* __restrict__ proj_w,
    const float* __restrict__ fc1_w, const float* __restrict__ fc2_w,
    const float* __restrict__ rpb_table, const int* __restrict__ rel_index,
    u16* wq, u16* wp, u16* w1, u16* w2, float* rpbf) {
  int i = blockIdx.x * 256 + threadIdx.x;
  if (i < 196608) { wq[i] = f2bf(qkv_w[i]); return; }
  int j = i - 196608;
  if (j < 65536) { wp[j] = f2bf(proj_w[j]); return; }
  int k = j - 65536;
  if (k < 262144) { w1[k] = f2bf(fc1_w[k]); return; }
  int l = k - 262144;
  if (l < 262144) { w2[l] = f2bf(fc2_w[l]); return; }
  int r = l - 262144;
  if (r < 8 * 2401) {
    int h = r / 2401, nm = r % 2401;
    rpbf[r] = rpb_table[rel_index[nm] * 8 + h];
  }
}

// ---------------- LN1 + cyclic shift + window partition -> bf16 ----------------
__global__ __launch_bounds__(256) void ln1_kernel(const float* __restrict__ x,
                                                  const float* __restrict__ gg,
                                                  const float* __restrict__ bb,
                                                  u16* __restrict__ y) {
  int wid = threadIdx.x >> 6, lane = threadIdx.x & 63;
  int m = blockIdx.x * 4 + wid;            // window-order token
  int win = m / 49, n = m % 49;
  int b = win >> 6, widx = win & 63;
  int hh = (widx >> 3) * 7 + n / 7 + 3; if (hh >= 56) hh -= 56;
  int ww = (widx & 7) * 7 + n % 7 + 3; if (ww >= 56) ww -= 56;
  const float* src = x + ((size_t)b * 3136 + hh * 56 + ww) * CDIM + lane * 4;
  float4 v = *(const float4*)src;
  float s = v.x + v.y + v.z + v.w;
  float s2 = v.x * v.x + v.y * v.y + v.z * v.z + v.w * v.w;
  for (int o = 32; o; o >>= 1) { s += __shfl_xor(s, o); s2 += __shfl_xor(s2, o); }
  float mean = s * (1.f / 256.f);
  float inv = rsqrtf(s2 * (1.f / 256.f) - mean * mean + 1e-5f);
  int c = lane * 4;
  float4 gv = *(const float4*)(gg + c);
  float4 bv = *(const float4*)(bb + c);
  U16x4 o4;
  o4.x = f2bf((v.x - mean) * inv * gv.x + bv.x);
  o4.y = f2bf((v.y - mean) * inv * gv.y + bv.y);
  o4.z = f2bf((v.z - mean) * inv * gv.z + bv.z);
  o4.w = f2bf((v.w - mean) * inv * gv.w + bv.w);
  *(U16x4*)(y + (size_t)m * CDIM + c) = o4;
}

// ---------------- LN2 (no gather), reads x2 (f32, in d_out) ----------------
__global__ __launch_bounds__(256) void ln2_kernel(const float* __restrict__ x2,
                                                  const float* __restrict__ gg,
                                                  const float* __restrict__ bb,
                                                  u16* __restrict__ y) {
  int wid = threadIdx.x >> 6, lane = threadIdx.x & 63;
  int m = blockIdx.x * 4 + wid;
  const float* src = x2 + (size_t)m * CDIM + lane * 4;
  float4 v = *(const float4*)src;
  float s = v.x + v.y + v.z + v.w;
  float s2 = v.x * v.x + v.y * v.y + v.z * v.z + v.w * v.w;
  for (int o = 32; o; o >>= 1) { s += __shfl_xor(s, o); s2 += __shfl_xor(s2, o); }
  float mean = s * (1.f / 256.f);
  float inv = rsqrtf(s2 * (1.f / 256.f) - mean * mean + 1e-5f);
  int c = lane * 4;
  float4 gv = *(const float4*)(gg + c);
  float4 bv = *(const float4*)(bb + c);
  U16x4 o4;
  o4.x = f2bf((v.x - mean) * inv * gv.x + bv.x);
  o4.y = f2bf((v.y - mean) * inv * gv.y + bv.y);
  o4.z = f2bf((v.z - mean) * inv * gv.z + bv.z);
  o4.w = f2bf((v.w - mean) * inv * gv.w + bv.w);
  *(U16x4*)(y + (size_t)m * CDIM + c) = o4;
}

// ---------------- 128x128 GEMM core: prefetch-dbuf + XOR-swizzled LDS ----------------
// C[128x128] = A[M,K] * B[N,K]^T at (m0,n0). 4 waves 2x2, wave owns 64x64.
// acc[i][j] = mfma(b_frag, a_frag)  =>  lane holds C[row = .. + lr][cols .. + g*4 + 0..3].
// LDS: 2 buffers x (A[128][32] + B[128][32]) bf16 = 32 KB.
// Swizzle: logical k-chunk g sits at physical slot g ^ ((row>>1)&3); stage reads
// the pre-swizzled GLOBAL chunk so gload_lds's linear dest lands correctly (rule #21).
template <int K>
__device__ __forceinline__ void gemm_tile(const u16* __restrict__ A, const u16* __restrict__ B,
                                          int m0, int n0, f32x4 acc[4][4], u16* lds) {
  const int tid = threadIdx.x;
  const int lane = tid & 63;
  const int lr = lane & 15, g = lane >> 4;
  const int wr = (tid >> 6) >> 1, wc = (tid >> 6) & 1;
  const int srow = tid >> 2;
  const int schunk = (tid & 3) ^ ((tid >> 3) & 3);   // pre-swizzled global k-chunk
  const u16* ga = A + (size_t)(m0 + srow) * K + schunk * 8;
  const u16* gb = B + (size_t)(n0 + srow) * K + schunk * 8;
  const int swz = (g ^ ((lr >> 1) & 3)) * 8;          // swizzled read slot

  auto STAGE = [&](int bsel, int k0) {
    u16* la = lds + bsel * 8192 + tid * 8;            // linear dest: base + lane*16B
    gload16(ga + k0, la);
    gload16(ga + (size_t)64 * K + k0, la + 2048);
    gload16(gb + k0, la + 4096);
    gload16(gb + (size_t)64 * K + k0, la + 6144);
  };
  auto COMPUTE = [&](int bsel) {
    const u16* ba = lds + bsel * 8192;
    const u16* bb = ba + 4096;
    bf16x8 af[4], bfr[4];
#pragma unroll
    for (int i = 0; i < 4; ++i) {
      af[i]  = *(const bf16x8*)(ba + (wr * 64 + i * 16 + lr) * 32 + swz);
      bfr[i] = *(const bf16x8*)(bb + (wc * 64 + i * 16 + lr) * 32 + swz);
    }
#pragma unroll
    for (int i = 0; i < 4; ++i)
#pragma unroll
      for (int j = 0; j < 4; ++j)
        acc[i][j] = __builtin_amdgcn_mfma_f32_16x16x32_bf16(bfr[j], af[i], acc[i][j], 0, 0, 0);
  };

  constexpr int NT = K / 32;   // even for all our K
  STAGE(0, 0);
  __syncthreads();
  for (int t = 0; t < NT; t += 2) {
    if (t + 1 < NT) STAGE(1, (t + 1) * 32);
    COMPUTE(0);
    __syncthreads();
    if (t + 2 < NT) STAGE(0, (t + 2) * 32);
    COMPUTE(1);
    __syncthreads();
  }
}

// XCD-aware swizzle (T1). nwg % 8 == 0 for all grids.
__device__ __forceinline__ int xcd_swz(int bid, int nwg) {
  return (bid & 7) * (nwg >> 3) + (bid >> 3);
}

#define GEMM_PROLOG(NVAL, KVAL)                                            \
  __shared__ u16 lds[16384];                                               \
  const int NTX = (NVAL) / 128;                                            \
  int logical = xcd_swz(blockIdx.x, NTX * (MTOK / 128));                   \
  int m0 = (logical / NTX) * 128, n0 = (logical % NTX) * 128;              \
  f32x4 zero = {0.f, 0.f, 0.f, 0.f};                                       \
  f32x4 acc[4][4] = {{zero, zero, zero, zero}, {zero, zero, zero, zero},   \
                     {zero, zero, zero, zero}, {zero, zero, zero, zero}};  \
  gemm_tile<KVAL>(A, B, m0, n0, acc, lds);                                 \
  const int lane = threadIdx.x & 63;                                       \
  const int lr = lane & 15, g = lane >> 4;                                 \
  const int wid = threadIdx.x >> 6, wr = wid >> 1, wc = wid & 1;

// qkv: out bf16 [M x 768], +bias. Lane holds rows ..+lr, 4 consecutive cols.
__global__ __launch_bounds__(256) void gemm_qkv(const u16* __restrict__ A, const u16* __restrict__ B,
                                                const float* __restrict__ bias, u16* __restrict__ out) {
  GEMM_PROLOG(NC3, 256)
#pragma unroll
  for (int i = 0; i < 4; ++i) {
    int row = m0 + wr * 64 + i * 16 + lr;
#pragma unroll
    for (int j = 0; j < 4; ++j) {
      int cb = n0 + wc * 64 + j * 16 + g * 4;
      U16x4 o4;
      o4.x = f2bf(acc[i][j][0] + bias[cb + 0]);
      o4.y = f2bf(acc[i][j][1] + bias[cb + 1]);
      o4.z = f2bf(acc[i][j][2] + bias[cb + 2]);
      o4.w = f2bf(acc[i][j][3] + bias[cb + 3]);
      *(U16x4*)(out + (size_t)row * NC3 + cb) = o4;
    }
  }
}

// proj: window-reverse + reverse-shift scatter, x2 = x + proj_out -> d_out (f32)
__global__ __launch_bounds__(256) void gemm_proj(const u16* __restrict__ A, const u16* __restrict__ B,
                                                 const float* __restrict__ bias,
                                                 const float* __restrict__ x, float* __restrict__ x2) {
  GEMM_PROLOG(CDIM, 256)
#pragma unroll
  for (int i = 0; i < 4; ++i) {
    int row = m0 + wr * 64 + i * 16 + lr;
    int win = row / 49, n = row % 49;
    int b = win >> 6, widx = win & 63;
    int hh = (widx >> 3) * 7 + n / 7 + 3; if (hh >= 56) hh -= 56;
    int ww = (widx & 7) * 7 + n % 7 + 3; if (ww >= 56) ww -= 56;
    size_t dst = ((size_t)b * 3136 + hh * 56 + ww) * CDIM;
#pragma unroll
    for (int j = 0; j < 4; ++j) {
      int cb = n0 + wc * 64 + j * 16 + g * 4;
      float4 xv = *(const float4*)(x + dst + cb);
      float4 bv = *(const float4*)(bias + cb);
      float4 o4;
      o4.x = xv.x + acc[i][j][0] + bv.x;
      o4.y = xv.y + acc[i][j][1] + bv.y;
      o4.z = xv.z + acc[i][j][2] + bv.z;
      o4.w = xv.w + acc[i][j][3] + bv.w;
      *(float4*)(x2 + dst + cb) = o4;
    }
  }
}

// fc1 + fast_gelu: out bf16 [M x 1024]
__global__ __launch_bounds__(256) void gemm_fc1(const u16* __restrict__ A, const u16* __restrict__ B,
                                                const float* __restrict__ bias, u16* __restrict__ out) {
  GEMM_PROLOG(HIDD, 256)
#pragma unroll
  for (int i = 0; i < 4; ++i) {
    int row = m0 + wr * 64 + i * 16 + lr;
#pragma unroll
    for (int j = 0; j < 4; ++j) {
      int cb = n0 + wc * 64 + j * 16 + g * 4;
      float4 bv = *(const float4*)(bias + cb);
      float v0 = acc[i][j][0] + bv.x, v1 = acc[i][j][1] + bv.y;
      float v2 = acc[i][j][2] + bv.z, v3 = acc[i][j][3] + bv.w;
      v0 = v0 / (1.f + __expf(-1.702f * v0));
      v1 = v1 / (1.f + __expf(-1.702f * v1));
      v2 = v2 / (1.f + __expf(-1.702f * v2));
      v3 = v3 / (1.f + __expf(-1.702f * v3));
      U16x4 o4 = {f2bf(v0), f2bf(v1), f2bf(v2), f2bf(v3)};
      *(U16x4*)(out + (size_t)row * HIDD + cb) = o4;
    }
  }
}

// fc2 + residual (in-place on d_out which holds x2)
__global__ __launch_bounds__(256) void gemm_fc2(const u16* __restrict__ A, const u16* __restrict__ B,
                                                const float* __restrict__ bias, float* __restrict__ out) {
  GEMM_PROLOG(CDIM, 1024)
#pragma unroll
  for (int i = 0; i < 4; ++i) {
    int row = m0 + wr * 64 + i * 16 + lr;
#pragma unroll
    for (int j = 0; j < 4; ++j) {
      int cb = n0 + wc * 64 + j * 16 + g * 4;
      float* p = out + (size_t)row * CDIM + cb;
      float4 ov = *(const float4*)p;
      float4 bv = *(const float4*)(bias + cb);
      ov.x += acc[i][j][0] + bv.x;
      ov.y += acc[i][j][1] + bv.y;
      ov.z += acc[i][j][2] + bv.z;
      ov.w += acc[i][j][3] + bv.w;
      *(float4*)p = ov;
    }
  }
}

// ---------------- windowed attention: 1 wave = 1 (window, head) ----------------
// Operand-swapped MFMAs: lane holds S[row=R*16+lr][col=Cc*16+g*4+reg] ->
// softmax = 16 in-lane values + shfl_xor(16,32); O stores are 8B u16x4.
__global__ __launch_bounds__(256) void attn_kernel(const u16* __restrict__ qkv,
                                                   const float* __restrict__ rpbf,
                                                   const float* __restrict__ mask,
                                                   u16* __restrict__ o) {
  __shared__ u16 p_lds[4][64][72];
  const int lane = threadIdx.x & 63, wid = threadIdx.x >> 6;
  const int lr = lane & 15, g = lane >> 4;
  const int win = blockIdx.x >> 1;
  const int head = (blockIdx.x & 1) * 4 + wid;
  const int widx = win & 63;
  const size_t base = (size_t)win * 49 * NC3 + head * 32;

  bf16x8 aq[4], bk[4];
#pragma unroll
  for (int R = 0; R < 4; ++R) {
    int n = R * 16 + lr; if (n > 48) n = 48;
    aq[R] = *(const bf16x8*)(qkv + base + (size_t)n * NC3 + 8 * g);
  }
#pragma unroll
  for (int Cc = 0; Cc < 4; ++Cc) {
    int mi = Cc * 16 + lr; if (mi > 48) mi = 48;
    bk[Cc] = *(const bf16x8*)(qkv + base + 256 + (size_t)mi * NC3 + 8 * g);
  }
  f32x4 zero = {0.f, 0.f, 0.f, 0.f};
  f32x4 s[4][4] = {{zero, zero, zero, zero}, {zero, zero, zero, zero},
                   {zero, zero, zero, zero}, {zero, zero, zero, zero}};
#pragma unroll
  for (int R = 0; R < 4; ++R)
#pragma unroll
    for (int Cc = 0; Cc < 4; ++Cc)
      s[R][Cc] = __builtin_amdgcn_mfma_f32_16x16x32_bf16(bk[Cc], aq[R], s[R][Cc], 0, 0, 0);

  const float scale = 0.17677669529663687f;  // 1/sqrt(32)
  const float* rpb_h = rpbf + head * 2401;
  const float* msk = mask + widx * 2401;
#pragma unroll
  for (int R = 0; R < 4; ++R) {
    int n = R * 16 + lr;          // this lane's S row for tile R
    bool nok = n < 49;
    int rbase = n * 49;
    float mx = -1e30f;
#pragma unroll
    for (int Cc = 0; Cc < 4; ++Cc)
#pragma unroll
      for (int reg = 0; reg < 4; ++reg) {
        int mc = Cc * 16 + g * 4 + reg;
        float v = (nok && mc < 49)
                    ? s[R][Cc][reg] * scale + rpb_h[rbase + mc] + msk[rbase + mc]
                    : -1e30f;
        s[R][Cc][reg] = v;
        mx = fmaxf(mx, v);
      }
    mx = fmaxf(mx, __shfl_xor(mx, 16));
    mx = fmaxf(mx, __shfl_xor(mx, 32));
    float sum = 0.f;
#pragma unroll
    for (int Cc = 0; Cc < 4; ++Cc)
#pragma unroll
      for (int reg = 0; reg < 4; ++reg) {
        float p = __expf(s[R][Cc][reg] - mx);
        s[R][Cc][reg] = p;
        sum += p;
      }
    sum += __shfl_xor(sum, 16);
    sum += __shfl_xor(sum, 32);
    float rs = 1.f / sum;
    int rowi = R * 16 + lr;
#pragma unroll
    for (int Cc = 0; Cc < 4; ++Cc) {
      U16x4 p4 = {f2bf(s[R][Cc][0] * rs), f2bf(s[R][Cc][1] * rs),
                  f2bf(s[R][Cc][2] * rs), f2bf(s[R][Cc][3] * rs)};
      *(U16x4*)(&p_lds[wid][rowi][Cc * 16 + g * 4]) = p4;
    }
  }
  __syncthreads();

  // O = P v  (swapped: oacc[R][D] lane holds O[row=R*16+lr][col=D*16+g*4+reg])
  f32x4 oacc[4][2] = {{zero, zero}, {zero, zero}, {zero, zero}, {zero, zero}};
  const u16* vbase = qkv + base + 512;
#pragma unroll
  for (int ks = 0; ks < 2; ++ks) {
    bf16x8 bv[2];
#pragma unroll
    for (int D = 0; D < 2; ++D) {
#pragma unroll
      for (int i = 0; i < 8; ++i) {
        int mi = ks * 32 + 8 * g + i; if (mi > 48) mi = 48;  // P[*][mi>=49]==0
        bv[D][i] = (short)vbase[(size_t)mi * NC3 + D * 16 + lr];
      }
    }
#pragma unroll
    for (int R = 0; R < 4; ++R) {
      bf16x8 ap = *(const bf16x8*)(&p_lds[wid][R * 16 + lr][ks * 32 + 8 * g]);
      oacc[R][0] = __builtin_amdgcn_mfma_f32_16x16x32_bf16(bv[0], ap, oacc[R][0], 0, 0, 0);
      oacc[R][1] = __builtin_amdgcn_mfma_f32_16x16x32_bf16(bv[1], ap, oacc[R][1], 0, 0, 0);
    }
  }
#pragma unroll
  for (int R = 0; R < 4; ++R) {
    int n = R * 16 + lr;
    if (n < 49) {
#pragma unroll
      for (int D = 0; D < 2; ++D) {
        U16x4 o4 = {f2bf(oacc[R][D][0]), f2bf(oacc[R][D][1]),
                    f2bf(oacc[R][D][2]), f2bf(oacc[R][D][3])};
        *(U16x4*)(o + ((size_t)win * 49 + n) * CDIM + head * 32 + D * 16 + g * 4) = o4;
      }
    }
  }
}

// ---------------- launch ----------------
extern "C" void kernel_launch(void* const* d_in, const int* in_sizes, int n_in,
                              void* d_out, int out_size, void* d_ws, size_t ws_size,
                              hipStream_t stream) {
  const float* x      = (const float*)d_in[0];
  const float* n1g    = (const float*)d_in[1];
  const float* n1b    = (const float*)d_in[2];
  const float* qkv_w  = (const float*)d_in[3];
  const float* qkv_b  = (const float*)d_in[4];
  const float* rpb_t  = (const float*)d_in[5];
  const float* proj_w = (const float*)d_in[6];
  const float* proj_b = (const float*)d_in[7];
  const float* n2g    = (const float*)d_in[8];
  const float* n2b    = (const float*)d_in[9];
  const float* fc1_w  = (const float*)d_in[10];
  const float* fc1_b  = (const float*)d_in[11];
  const float* fc2_w  = (const float*)d_in[12];
  const float* fc2_b  = (const float*)d_in[13];
  const int*   relidx = (const int*)d_in[14];
  const float* amask  = (const float*)d_in[15];
  float* out = (float*)d_out;
  char* ws = (char*)d_ws;

  u16* qkv_buf = (u16*)(ws + OFF_QKV);
  u16* o_buf   = (u16*)(ws + OFF_O);
  u16* h1_buf  = (u16*)(ws + OFF_H1);
  u16* y_buf   = (u16*)(ws + OFF_Y);
  u16* wq = (u16*)(ws + OFF_WQ);
  u16* wp = (u16*)(ws + OFF_WP);
  u16* w1 = (u16*)(ws + OFF_W1);
  u16* w2 = (u16*)(ws + OFF_W2);
  float* rpbf = (float*)(ws + OFF_RPB);

  prep_kernel<<<3148, 256, 0, stream>>>(qkv_w, proj_w, fc1_w, fc2_w, rpb_t, relidx, wq, wp, w1, w2, rpbf);
  ln1_kernel<<<MTOK / 4, 256, 0, stream>>>(x, n1g, n1b, y_buf);
  gemm_qkv<<<(NC3 / 128) * (MTOK / 128), 256, 0, stream>>>(y_buf, wq, qkv_b, qkv_buf);
  attn_kernel<<<4096 * 2, 256, 0, stream>>>(qkv_buf, rpbf, amask, o_buf);
  gemm_proj<<<(CDIM / 128) * (MTOK / 128), 256, 0, stream>>>(o_buf, wp, proj_b, x, out);
  ln2_kernel<<<MTOK / 4, 256, 0, stream>>>(out, n2g, n2b, y_buf);
  gemm_fc1<<<(HIDD / 128) * (MTOK / 128), 256, 0, stream>>>(y_buf, w1, fc1_b, h1_buf);
  gemm_fc2<<<(CDIM / 128) * (MTOK / 128), 256, 0, stream>>>(h1_buf, w2, fc2_b, out);
}

// Round 5
// 1343.246 us; speedup vs baseline: 1.7312x; 1.0063x over previous
//
#include <hip/hip_runtime.h>
#include <hip/hip_bf16.h>

typedef unsigned short u16;
typedef __attribute__((ext_vector_type(8))) short bf16x8;
typedef __attribute__((ext_vector_type(4))) float f32x4;

struct __align__(8) U16x4 { u16 x, y, z, w; };

__device__ __forceinline__ u16 f2bf(float f) {
  __hip_bfloat16 h = __float2bfloat16(f);   // RNE; compiler can pack to v_cvt_pk_bf16_f32
  u16 r;
  __builtin_memcpy(&r, &h, 2);
  return r;
}

// async global->LDS, 16B per lane (global_load_lds_dwordx4)
__device__ __forceinline__ void gload16(const u16* g, u16* l) {
  __builtin_amdgcn_global_load_lds((const __attribute__((address_space(1))) void*)g,
                                   (__attribute__((address_space(3))) void*)l, 16, 0, 0);
}

// ---------------- constants ----------------
#define MTOK 200704
#define CDIM 256
#define NC3  768
#define HIDD 1024

// ws layout (bytes)
#define OFF_QKV   0UL
#define OFF_O     308281344UL
#define OFF_H1    0UL
#define OFF_Y     411041792UL
#define OFF_WQ    513802240UL
#define OFF_WP    514195456UL
#define OFF_W1    514326528UL
#define OFF_W2    514850816UL
#define OFF_RPB   515375104UL

// ---------------- prep: weights f32->bf16, rpb gather ----------------
__global__ __launch_bounds__(256) void prep_kernel(
    const float* __restrict__ qkv_w, const float* __restrict__ proj_w,
    const float* __restrict__ fc1_w, const float* __restrict__ fc2_w,
    const float* __restrict__ rpb_table, const int* __restrict__ rel_index,
    u16* wq, u16* wp, u16* w1, u16* w2, float* rpbf) {
  int i = blockIdx.x * 256 + threadIdx.x;
  if (i < 196608) { wq[i] = f2bf(qkv_w[i]); return; }
  int j = i - 196608;
  if (j < 65536) { wp[j] = f2bf(proj_w[j]); return; }
  int k = j - 65536;
  if (k < 262144) { w1[k] = f2bf(fc1_w[k]); return; }
  int l = k - 262144;
  if (l < 262144) { w2[l] = f2bf(fc2_w[l]); return; }
  int r = l - 262144;
  if (r < 8 * 2401) {
    int h = r / 2401, nm = r % 2401;
    rpbf[r] = rpb_table[rel_index[nm] * 8 + h];
  }
}

// ---------------- LN1 + cyclic shift + window partition -> bf16 ----------------
__global__ __launch_bounds__(256) void ln1_kernel(const float* __restrict__ x,
                                                  const float* __restrict__ gg,
                                                  const float* __restrict__ bb,
                                                  u16* __restrict__ y) {
  int wid = threadIdx.x >> 6, lane = threadIdx.x & 63;
  int m = blockIdx.x * 4 + wid;            // window-order token
  int win = m / 49, n = m % 49;
  int b = win >> 6, widx = win & 63;
  int hh = (widx >> 3) * 7 + n / 7 + 3; if (hh >= 56) hh -= 56;
  int ww = (widx & 7) * 7 + n % 7 + 3; if (ww >= 56) ww -= 56;
  const float* src = x + ((size_t)b * 3136 + hh * 56 + ww) * CDIM + lane * 4;
  float4 v = *(const float4*)src;
  float s = v.x + v.y + v.z + v.w;
  float s2 = v.x * v.x + v.y * v.y + v.z * v.z + v.w * v.w;
  for (int o = 32; o; o >>= 1) { s += __shfl_xor(s, o); s2 += __shfl_xor(s2, o); }
  float mean = s * (1.f / 256.f);
  float inv = rsqrtf(s2 * (1.f / 256.f) - mean * mean + 1e-5f);
  int c = lane * 4;
  float4 gv = *(const float4*)(gg + c);
  float4 bv = *(const float4*)(bb + c);
  U16x4 o4;
  o4.x = f2bf((v.x - mean) * inv * gv.x + bv.x);
  o4.y = f2bf((v.y - mean) * inv * gv.y + bv.y);
  o4.z = f2bf((v.z - mean) * inv * gv.z + bv.z);
  o4.w = f2bf((v.w - mean) * inv * gv.w + bv.w);
  *(U16x4*)(y + (size_t)m * CDIM + c) = o4;
}

// ---------------- LN2 (no gather), reads x2 (f32, in d_out) ----------------
__global__ __launch_bounds__(256) void ln2_kernel(const float* __restrict__ x2,
                                                  const float* __restrict__ gg,
                                                  const float* __restrict__ bb,
                                                  u16* __restrict__ y) {
  int wid = threadIdx.x >> 6, lane = threadIdx.x & 63;
  int m = blockIdx.x * 4 + wid;
  const float* src = x2 + (size_t)m * CDIM + lane * 4;
  float4 v = *(const float4*)src;
  float s = v.x + v.y + v.z + v.w;
  float s2 = v.x * v.x + v.y * v.y + v.z * v.z + v.w * v.w;
  for (int o = 32; o; o >>= 1) { s += __shfl_xor(s, o); s2 += __shfl_xor(s2, o); }
  float mean = s * (1.f / 256.f);
  float inv = rsqrtf(s2 * (1.f / 256.f) - mean * mean + 1e-5f);
  int c = lane * 4;
  float4 gv = *(const float4*)(gg + c);
  float4 bv = *(const float4*)(bb + c);
  U16x4 o4;
  o4.x = f2bf((v.x - mean) * inv * gv.x + bv.x);
  o4.y = f2bf((v.y - mean) * inv * gv.y + bv.y);
  o4.z = f2bf((v.z - mean) * inv * gv.z + bv.z);
  o4.w = f2bf((v.w - mean) * inv * gv.w + bv.w);
  *(U16x4*)(y + (size_t)m * CDIM + c) = o4;
}

// ---------------- 128x128 GEMM core v3: 3-buf counted-vmcnt pipeline ----------------
// C[128x128] = A[M,K] * B[N,K]^T at (m0,n0). 4 waves 2x2, wave owns 64x64.
// acc[i][j] = mfma(b_frag, a_frag) => lane holds C[row=..+lr][cols ..+g*4+0..3].
// LDS: 3 buffers x (A[128][32] + B[128][32]) bf16 = 48 KB. Prefetch distance 2.
// Per K-step: {vmcnt(4); s_barrier; STAGE(t+2); 8 ds_read_b128; 16 MFMA} -
// stages stay in flight across barriers (T3/T4), never drain to 0 mid-loop.
// Safety: buf (t+2)%3 was read in iter t-1; those ds_reads complete before each
// wave's MFMAs there (compiler lgkm waits), hence before barrier(t) < STAGE(t+2).
template <int K>
__device__ __forceinline__ void gemm_tile(const u16* __restrict__ A, const u16* __restrict__ B,
                                          int m0, int n0, f32x4 acc[4][4], u16* lds) {
  const int tid = threadIdx.x;
  const int lane = tid & 63;
  const int lr = lane & 15, g = lane >> 4;
  const int wr = (tid >> 6) >> 1, wc = (tid >> 6) & 1;
  const int srow = tid >> 2;
  const int schunk = (tid & 3) ^ ((tid >> 3) & 3);   // pre-swizzled global k-chunk
  const u16* ga = A + (size_t)(m0 + srow) * K + schunk * 8;
  const u16* gb = B + (size_t)(n0 + srow) * K + schunk * 8;
  const int swz = (g ^ ((lr >> 1) & 3)) * 8;          // swizzled read slot
  const int aoff = (wr * 64 + lr) * 32 + swz;         // + i*512 per 16-row frag
  const int boff = (wc * 64 + lr) * 32 + swz;

  auto STAGE = [&](int bsel, int k0) {
    u16* la = lds + bsel * 8192 + tid * 8;            // linear dest: base + lane*16B
    gload16(ga + k0, la);
    gload16(ga + (size_t)64 * K + k0, la + 2048);
    gload16(gb + k0, la + 4096);
    gload16(gb + (size_t)64 * K + k0, la + 6144);
  };

  constexpr int NT = K / 32;   // >= 8 for all our K
  STAGE(0, 0);
  STAGE(1, 32);
#pragma unroll
  for (int t = 0; t < NT; ++t) {
    if (t < NT - 1) asm volatile("s_waitcnt vmcnt(4)" ::: "memory");
    else            asm volatile("s_waitcnt vmcnt(0)" ::: "memory");
    __builtin_amdgcn_s_barrier();
    __builtin_amdgcn_sched_barrier(0);
    if (t < NT - 2) STAGE((t + 2) % 3, (t + 2) * 32);
    const u16* ba = lds + (t % 3) * 8192;
    const u16* bb = ba + 4096;
    bf16x8 af[4], bfr[4];
#pragma unroll
    for (int i = 0; i < 4; ++i) {
      af[i]  = *(const bf16x8*)(ba + aoff + i * 512);
      bfr[i] = *(const bf16x8*)(bb + boff + i * 512);
    }
#pragma unroll
    for (int i = 0; i < 4; ++i)
#pragma unroll
      for (int j = 0; j < 4; ++j)
        acc[i][j] = __builtin_amdgcn_mfma_f32_16x16x32_bf16(bfr[j], af[i], acc[i][j], 0, 0, 0);
  }
}

// XCD-aware swizzle (T1). nwg % 8 == 0 for all grids.
__device__ __forceinline__ int xcd_swz(int bid, int nwg) {
  return (bid & 7) * (nwg >> 3) + (bid >> 3);
}

#define GEMM_PROLOG(NVAL, KVAL)                                            \
  __shared__ u16 lds[24576];                                               \
  const int NTX = (NVAL) / 128;                                            \
  int logical = xcd_swz(blockIdx.x, NTX * (MTOK / 128));                   \
  int m0 = (logical / NTX) * 128, n0 = (logical % NTX) * 128;              \
  f32x4 zero = {0.f, 0.f, 0.f, 0.f};                                       \
  f32x4 acc[4][4] = {{zero, zero, zero, zero}, {zero, zero, zero, zero},   \
                     {zero, zero, zero, zero}, {zero, zero, zero, zero}};  \
  gemm_tile<KVAL>(A, B, m0, n0, acc, lds);                                 \
  const int lane = threadIdx.x & 63;                                       \
  const int lr = lane & 15, g = lane >> 4;                                 \
  const int wid = threadIdx.x >> 6, wr = wid >> 1, wc = wid & 1;

// qkv: out bf16 [M x 768], +bias. Lane holds rows ..+lr, 4 consecutive cols.
__global__ __launch_bounds__(256) void gemm_qkv(const u16* __restrict__ A, const u16* __restrict__ B,
                                                const float* __restrict__ bias, u16* __restrict__ out) {
  GEMM_PROLOG(NC3, 256)
#pragma unroll
  for (int i = 0; i < 4; ++i) {
    int row = m0 + wr * 64 + i * 16 + lr;
#pragma unroll
    for (int j = 0; j < 4; ++j) {
      int cb = n0 + wc * 64 + j * 16 + g * 4;
      U16x4 o4;
      o4.x = f2bf(acc[i][j][0] + bias[cb + 0]);
      o4.y = f2bf(acc[i][j][1] + bias[cb + 1]);
      o4.z = f2bf(acc[i][j][2] + bias[cb + 2]);
      o4.w = f2bf(acc[i][j][3] + bias[cb + 3]);
      *(U16x4*)(out + (size_t)row * NC3 + cb) = o4;
    }
  }
}

// proj: window-reverse + reverse-shift scatter, x2 = x + proj_out -> d_out (f32)
__global__ __launch_bounds__(256) void gemm_proj(const u16* __restrict__ A, const u16* __restrict__ B,
                                                 const float* __restrict__ bias,
                                                 const float* __restrict__ x, float* __restrict__ x2) {
  GEMM_PROLOG(CDIM, 256)
#pragma unroll
  for (int i = 0; i < 4; ++i) {
    int row = m0 + wr * 64 + i * 16 + lr;
    int win = row / 49, n = row % 49;
    int b = win >> 6, widx = win & 63;
    int hh = (widx >> 3) * 7 + n / 7 + 3; if (hh >= 56) hh -= 56;
    int ww = (widx & 7) * 7 + n % 7 + 3; if (ww >= 56) ww -= 56;
    size_t dst = ((size_t)b * 3136 + hh * 56 + ww) * CDIM;
#pragma unroll
    for (int j = 0; j < 4; ++j) {
      int cb = n0 + wc * 64 + j * 16 + g * 4;
      float4 xv = *(const float4*)(x + dst + cb);
      float4 bv = *(const float4*)(bias + cb);
      float4 o4;
      o4.x = xv.x + acc[i][j][0] + bv.x;
      o4.y = xv.y + acc[i][j][1] + bv.y;
      o4.z = xv.z + acc[i][j][2] + bv.z;
      o4.w = xv.w + acc[i][j][3] + bv.w;
      *(float4*)(x2 + dst + cb) = o4;
    }
  }
}

// fc1 + fast_gelu: out bf16 [M x 1024]
__global__ __launch_bounds__(256) void gemm_fc1(const u16* __restrict__ A, const u16* __restrict__ B,
                                                const float* __restrict__ bias, u16* __restrict__ out) {
  GEMM_PROLOG(HIDD, 256)
#pragma unroll
  for (int i = 0; i < 4; ++i) {
    int row = m0 + wr * 64 + i * 16 + lr;
#pragma unroll
    for (int j = 0; j < 4; ++j) {
      int cb = n0 + wc * 64 + j * 16 + g * 4;
      float4 bv = *(const float4*)(bias + cb);
      float v0 = acc[i][j][0] + bv.x, v1 = acc[i][j][1] + bv.y;
      float v2 = acc[i][j][2] + bv.z, v3 = acc[i][j][3] + bv.w;
      v0 = v0 / (1.f + __expf(-1.702f * v0));
      v1 = v1 / (1.f + __expf(-1.702f * v1));
      v2 = v2 / (1.f + __expf(-1.702f * v2));
      v3 = v3 / (1.f + __expf(-1.702f * v3));
      U16x4 o4 = {f2bf(v0), f2bf(v1), f2bf(v2), f2bf(v3)};
      *(U16x4*)(out + (size_t)row * HIDD + cb) = o4;
    }
  }
}

// fc2 + residual (in-place on d_out which holds x2)
__global__ __launch_bounds__(256) void gemm_fc2(const u16* __restrict__ A, const u16* __restrict__ B,
                                                const float* __restrict__ bias, float* __restrict__ out) {
  GEMM_PROLOG(CDIM, 1024)
#pragma unroll
  for (int i = 0; i < 4; ++i) {
    int row = m0 + wr * 64 + i * 16 + lr;
#pragma unroll
    for (int j = 0; j < 4; ++j) {
      int cb = n0 + wc * 64 + j * 16 + g * 4;
      float* p = out + (size_t)row * CDIM + cb;
      float4 ov = *(const float4*)p;
      float4 bv = *(const float4*)(bias + cb);
      ov.x += acc[i][j][0] + bv.x;
      ov.y += acc[i][j][1] + bv.y;
      ov.z += acc[i][j][2] + bv.z;
      ov.w += acc[i][j][3] + bv.w;
      *(float4*)p = ov;
    }
  }
}

// ---------------- windowed attention: 1 wave = 1 (window, head) ----------------
// Operand-swapped MFMAs: lane holds S[row=R*16+lr][col=Cc*16+g*4+reg] ->
// softmax = 16 in-lane values + shfl_xor(16,32); O stores are 8B u16x4.
__global__ __launch_bounds__(256) void attn_kernel(const u16* __restrict__ qkv,
                                                   const float* __restrict__ rpbf,
                                                   const float* __restrict__ mask,
                                                   u16* __restrict__ o) {
  __shared__ u16 p_lds[4][64][72];
  const int lane = threadIdx.x & 63, wid = threadIdx.x >> 6;
  const int lr = lane & 15, g = lane >> 4;
  const int win = blockIdx.x >> 1;
  const int head = (blockIdx.x & 1) * 4 + wid;
  const int widx = win & 63;
  const size_t base = (size_t)win * 49 * NC3 + head * 32;

  bf16x8 aq[4], bk[4];
#pragma unroll
  for (int R = 0; R < 4; ++R) {
    int n = R * 16 + lr; if (n > 48) n = 48;
    aq[R] = *(const bf16x8*)(qkv + base + (size_t)n * NC3 + 8 * g);
  }
#pragma unroll
  for (int Cc = 0; Cc < 4; ++Cc) {
    int mi = Cc * 16 + lr; if (mi > 48) mi = 48;
    bk[Cc] = *(const bf16x8*)(qkv + base + 256 + (size_t)mi * NC3 + 8 * g);
  }
  f32x4 zero = {0.f, 0.f, 0.f, 0.f};
  f32x4 s[4][4] = {{zero, zero, zero, zero}, {zero, zero, zero, zero},
                   {zero, zero, zero, zero}, {zero, zero, zero, zero}};
#pragma unroll
  for (int R = 0; R < 4; ++R)
#pragma unroll
    for (int Cc = 0; Cc < 4; ++Cc)
      s[R][Cc] = __builtin_amdgcn_mfma_f32_16x16x32_bf16(bk[Cc], aq[R], s[R][Cc], 0, 0, 0);

  const float scale = 0.17677669529663687f;  // 1/sqrt(32)
  const float* rpb_h = rpbf + head * 2401;
  const float* msk = mask + widx * 2401;
#pragma unroll
  for (int R = 0; R < 4; ++R) {
    int n = R * 16 + lr;          // this lane's S row for tile R
    bool nok = n < 49;
    int rbase = n * 49;
    float mx = -1e30f;
#pragma unroll
    for (int Cc = 0; Cc < 4; ++Cc)
#pragma unroll
      for (int reg = 0; reg < 4; ++reg) {
        int mc = Cc * 16 + g * 4 + reg;
        float v = (nok && mc < 49)
                    ? s[R][Cc][reg] * scale + rpb_h[rbase + mc] + msk[rbase + mc]
                    : -1e30f;
        s[R][Cc][reg] = v;
        mx = fmaxf(mx, v);
      }
    mx = fmaxf(mx, __shfl_xor(mx, 16));
    mx = fmaxf(mx, __shfl_xor(mx, 32));
    float sum = 0.f;
#pragma unroll
    for (int Cc = 0; Cc < 4; ++Cc)
#pragma unroll
      for (int reg = 0; reg < 4; ++reg) {
        float p = __expf(s[R][Cc][reg] - mx);
        s[R][Cc][reg] = p;
        sum += p;
      }
    sum += __shfl_xor(sum, 16);
    sum += __shfl_xor(sum, 32);
    float rs = 1.f / sum;
    int rowi = R * 16 + lr;
#pragma unroll
    for (int Cc = 0; Cc < 4; ++Cc) {
      U16x4 p4 = {f2bf(s[R][Cc][0] * rs), f2bf(s[R][Cc][1] * rs),
                  f2bf(s[R][Cc][2] * rs), f2bf(s[R][Cc][3] * rs)};
      *(U16x4*)(&p_lds[wid][rowi][Cc * 16 + g * 4]) = p4;
    }
  }
  __syncthreads();

  // O = P v  (swapped: oacc[R][D] lane holds O[row=R*16+lr][col=D*16+g*4+reg])
  f32x4 oacc[4][2] = {{zero, zero}, {zero, zero}, {zero, zero}, {zero, zero}};
  const u16* vbase = qkv + base + 512;
#pragma unroll
  for (int ks = 0; ks < 2; ++ks) {
    bf16x8 bv[2];
#pragma unroll
    for (int D = 0; D < 2; ++D) {
#pragma unroll
      for (int i = 0; i < 8; ++i) {
        int mi = ks * 32 + 8 * g + i; if (mi > 48) mi = 48;  // P[*][mi>=49]==0
        bv[D][i] = (short)vbase[(size_t)mi * NC3 + D * 16 + lr];
      }
    }
#pragma unroll
    for (int R = 0; R < 4; ++R) {
      bf16x8 ap = *(const bf16x8*)(&p_lds[wid][R * 16 + lr][ks * 32 + 8 * g]);
      oacc[R][0] = __builtin_amdgcn_mfma_f32_16x16x32_bf16(bv[0], ap, oacc[R][0], 0, 0, 0);
      oacc[R][1] = __builtin_amdgcn_mfma_f32_16x16x32_bf16(bv[1], ap, oacc[R][1], 0, 0, 0);
    }
  }
#pragma unroll
  for (int R = 0; R < 4; ++R) {
    int n = R * 16 + lr;
    if (n < 49) {
#pragma unroll
      for (int D = 0; D < 2; ++D) {
        U16x4 o4 = {f2bf(oacc[R][D][0]), f2bf(oacc[R][D][1]),
                    f2bf(oacc[R][D][2]), f2bf(oacc[R][D][3])};
        *(U16x4*)(o + ((size_t)win * 49 + n) * CDIM + head * 32 + D * 16 + g * 4) = o4;
      }
    }
  }
}

// ---------------- launch ----------------
extern "C" void kernel_launch(void* const* d_in, const int* in_sizes, int n_in,
                              void* d_out, int out_size, void* d_ws, size_t ws_size,
                              hipStream_t stream) {
  const float* x      = (const float*)d_in[0];
  const float* n1g    = (const float*)d_in[1];
  const float* n1b    = (const float*)d_in[2];
  const float* qkv_w  = (const float*)d_in[3];
  const float* qkv_b  = (const float*)d_in[4];
  const float* rpb_t  = (const float*)d_in[5];
  const float* proj_w = (const float*)d_in[6];
  const float* proj_b = (const float*)d_in[7];
  const float* n2g    = (const float*)d_in[8];
  const float* n2b    = (const float*)d_in[9];
  const float* fc1_w  = (const float*)d_in[10];
  const float* fc1_b  = (const float*)d_in[11];
  const float* fc2_w  = (const float*)d_in[12];
  const float* fc2_b  = (const float*)d_in[13];
  const int*   relidx = (const int*)d_in[14];
  const float* amask  = (const float*)d_in[15];
  float* out = (float*)d_out;
  char* ws = (char*)d_ws;

  u16* qkv_buf = (u16*)(ws + OFF_QKV);
  u16* o_buf   = (u16*)(ws + OFF_O);
  u16* h1_buf  = (u16*)(ws + OFF_H1);
  u16* y_buf   = (u16*)(ws + OFF_Y);
  u16* wq = (u16*)(ws + OFF_WQ);
  u16* wp = (u16*)(ws + OFF_WP);
  u16* w1 = (u16*)(ws + OFF_W1);
  u16* w2 = (u16*)(ws + OFF_W2);
  float* rpbf = (float*)(ws + OFF_RPB);

  prep_kernel<<<3148, 256, 0, stream>>>(qkv_w, proj_w, fc1_w, fc2_w, rpb_t, relidx, wq, wp, w1, w2, rpbf);
  ln1_kernel<<<MTOK / 4, 256, 0, stream>>>(x, n1g, n1b, y_buf);
  gemm_qkv<<<(NC3 / 128) * (MTOK / 128), 256, 0, stream>>>(y_buf, wq, qkv_b, qkv_buf);
  attn_kernel<<<4096 * 2, 256, 0, stream>>>(qkv_buf, rpbf, amask, o_buf);
  gemm_proj<<<(CDIM / 128) * (MTOK / 128), 256, 0, stream>>>(o_buf, wp, proj_b, x, out);
  ln2_kernel<<<MTOK / 4, 256, 0, stream>>>(out, n2g, n2b, y_buf);
  gemm_fc1<<<(HIDD / 128) * (MTOK / 128), 256, 0, stream>>>(y_buf, w1, fc1_b, h1_buf);
  gemm_fc2<<<(CDIM / 128) * (MTOK / 128), 256, 0, stream>>>(h1_buf, w2, fc2_b, out);
}